// Round 10
// baseline (230.202 us; speedup 1.0000x reference)
//
#include <hip/hip_runtime.h>
#include <hip/hip_bf16.h>

// RelationsNetwork on MI355X.
// Decomposition: h1 = relu(u[j] + v[i] + (x_i*x_j)@W_c + b1), u=x@W_a, v=x@W_b
// where g_w1 = [W_a; W_b; W_c] (rows 0:258, 258:516, 516:774).
// Round-10: occupancy via SMALL blocks, not big ones. r9 (512thr, 128-reg cap)
// spilled 27MB and regressed; this round: block=(b,i) M=64 (2048 blocks),
// 256 thr, wave = mt2 x nt2 (64 rows x 64 cols), acc = 64 AGPR.
// LDS = max(A 64x280, H 64x256) = 35840 B -> 4 blocks/CU by LDS.
// __launch_bounds__(256,3): 170-reg cap (no spill possible); if actual
// total <=128 the HW gives 16 waves/CU, else 12 — both > r8's 8.
// Register diet: runtime (non-unrolled) staging loop, B-only 1-deep prefetch.
// Cost: M=64 doubles L2 weight streaming (~820MB, ~23us) — hidden by TLP.
// Packed bf16 staging/epilogues (r8-proven). 5 barriers.

typedef __attribute__((ext_vector_type(4))) float f32x4;
typedef __attribute__((ext_vector_type(16))) float f32x16;
typedef __attribute__((ext_vector_type(8))) short frag8;   // 8 bf16 = 4 VGPR
typedef __attribute__((ext_vector_type(4))) unsigned u32x4;

__device__ __forceinline__ float bf2f(short s) {
  return __uint_as_float(((unsigned)(unsigned short)s) << 16);
}
__device__ __forceinline__ short f2bf(float f) {
  unsigned u = __float_as_uint(f);
  return (short)((u + 0x7fffu + ((u >> 16) & 1u)) >> 16);
}

// pack two f32 -> one dword of two bf16 (lo, hi), RNE
__device__ __forceinline__ unsigned pk_bf16(float lo, float hi) {
#if __has_builtin(__builtin_amdgcn_cvt_pk_bf16_f32)
  return __builtin_bit_cast(unsigned, __builtin_amdgcn_cvt_pk_bf16_f32(lo, hi));
#else
  unsigned ul = __float_as_uint(lo), uh = __float_as_uint(hi);
  ul = (ul + 0x7fffu + ((ul >> 16) & 1u)) >> 16;
  uh = (uh + 0x7fffu + ((uh >> 16) & 1u)) & 0xffff0000u;
  return ul | uh;
#endif
}

// elementwise bf16 product of two bf16x2 dwords
__device__ __forceinline__ unsigned pk_mul_bf16(unsigned a, unsigned b) {
  float al = __uint_as_float(a << 16);
  float ah = __uint_as_float(a & 0xffff0000u);
  float bl = __uint_as_float(b << 16);
  float bh = __uint_as_float(b & 0xffff0000u);
  return pk_bf16(al * bl, ah * bh);
}

__device__ __forceinline__ frag8 pk_mul4(u32x4 a, u32x4 b) {
  u32x4 r;
#pragma unroll
  for (int t = 0; t < 4; t++) r[t] = pk_mul_bf16(a[t], b[t]);
  return __builtin_bit_cast(frag8, r);
}

#define KX 288   // xb row stride (padded); K iterated = 272 (17 steps)

// ---------------- merged prep kernel ----------------
// regions by blockIdx.x:
//   [0,288)    build_x:  xb[(b*64+s)*288+k] = bf16(x[b,s,k])
//   [288,328)  Wab:  [n][k] n<256 -> W_a col n ; n>=256 -> W_b col n-256
//   [328,348)  Wc:   [n][k] = g_w1[516+k][n]
//   [348,364)  W2t:  [n][k] = g_w2[k][n]
//   [364,380)  W3t:  [n][k] = g_w3[k][n]
//   [380,388)  zero rel
__global__ __launch_bounds__(256)
void prep(const float* __restrict__ sent, const float* __restrict__ coord,
          const float* __restrict__ g_w1, const float* __restrict__ g_w2,
          const float* __restrict__ g_w3,
          short* __restrict__ xb, short* __restrict__ Wab, short* __restrict__ Wc,
          short* __restrict__ W2t, short* __restrict__ W3t, float* __restrict__ rel) {
  __shared__ short tile[64 * 66];  // odd-dword stride: conflict-free transpose
  const int blk = blockIdx.x, t = threadIdx.x;

  if (blk < 288) {
    long idx0 = ((long)blk * 256 + t) * 8;
#pragma unroll
    for (int e = 0; e < 8; e++) {
      long idx = idx0 + e;
      int row = (int)(idx / KX), k = (int)(idx - (long)row * KX);
      float v = 0.f;
      if (k < 256)      v = sent[(size_t)row * 256 + k];
      else if (k < 258) v = coord[row * 2 + (k - 256)];
      xb[idx] = f2bf(v);
    }
    return;
  }

  const int nc = t & 63, r4 = t >> 6;  // read: 4 rows x 64 cols per pass
  if (blk < 328) {  // Wab
    int tt = blk - 288, kt = tt >> 3, nt = tt & 7;
    int k0 = kt * 64, n0 = nt * 64;
    for (int p = 0; p < 16; p++) {
      int kl = p * 4 + r4, k = k0 + kl, n = n0 + nc;
      float v = 0.f;
      if (k < 258) {
        int row = (n < 256) ? k : 258 + k;
        int col = (n < 256) ? n : n - 256;
        v = g_w1[(size_t)row * 256 + col];
      }
      tile[kl * 66 + nc] = f2bf(v);
    }
    __syncthreads();
    for (int p = 0; p < 16; p++) {
      int nl = p * 4 + r4;
      if (k0 + nc < KX) Wab[(size_t)(n0 + nl) * KX + k0 + nc] = tile[nc * 66 + nl];
    }
    return;
  }
  if (blk < 348) {  // Wc
    int tt = blk - 328, kt = tt >> 2, nt = tt & 3;
    int k0 = kt * 64, n0 = nt * 64;
    for (int p = 0; p < 16; p++) {
      int kl = p * 4 + r4, k = k0 + kl;
      float v = (k < 258) ? g_w1[(size_t)(516 + k) * 256 + n0 + nc] : 0.f;
      tile[kl * 66 + nc] = f2bf(v);
    }
    __syncthreads();
    for (int p = 0; p < 16; p++) {
      int nl = p * 4 + r4;
      if (k0 + nc < KX) Wc[(size_t)(n0 + nl) * KX + k0 + nc] = tile[nc * 66 + nl];
    }
    return;
  }
  if (blk < 380) {  // W2t / W3t
    int tt = blk - 348;
    const float* W = (tt < 16) ? g_w2 : g_w3;
    short* Wt = (tt < 16) ? W2t : W3t;
    tt &= 15;
    int k0 = (tt >> 2) * 64, n0 = (tt & 3) * 64;
    for (int p = 0; p < 16; p++) {
      int kl = p * 4 + r4;
      tile[kl * 66 + nc] = f2bf(W[(size_t)(k0 + kl) * 256 + n0 + nc]);
    }
    __syncthreads();
    for (int p = 0; p < 16; p++) {
      int nl = p * 4 + r4;
      Wt[(size_t)(n0 + nl) * 256 + k0 + nc] = tile[nc * 66 + nl];
    }
    return;
  }
  // zero rel: 8 blocks x 256 threads x 1 float4
  {
    int bb = blk - 380;
    ((f32x4*)rel)[bb * 256 + t] = (f32x4){0.f, 0.f, 0.f, 0.f};
  }
}

// ---------------- u/v GEMM: uv[m][0:256]=x@W_a, uv[m][256:512]=x@W_b + b1 ----------------
// one wave per block, 256 blocks (32 m-tiles x 8 n-tiles); 16x16x32 (known-good)

__global__ __launch_bounds__(64)
void uv_gemm(const short* __restrict__ xb, const short* __restrict__ Wab,
             const float* __restrict__ g_b1, float* __restrict__ uv) {
  const int m0 = blockIdx.x * 64;
  const int n0 = blockIdx.y * 64;
  const int lane = threadIdx.x;
  const int q = lane >> 4, l16 = lane & 15;

  f32x4 acc[4][4];
#pragma unroll
  for (int mt = 0; mt < 4; mt++)
#pragma unroll
    for (int nt = 0; nt < 4; nt++) acc[mt][nt] = (f32x4){0.f, 0.f, 0.f, 0.f};

  for (int k0 = 0; k0 < KX; k0 += 32) {
    frag8 a[4], bb[4];
#pragma unroll
    for (int mt = 0; mt < 4; mt++)
      a[mt] = *(const frag8*)(xb + (size_t)(m0 + mt * 16 + l16) * KX + k0 + q * 8);
#pragma unroll
    for (int nt = 0; nt < 4; nt++)
      bb[nt] = *(const frag8*)(Wab + (size_t)(n0 + nt * 16 + l16) * KX + k0 + q * 8);
#pragma unroll
    for (int mt = 0; mt < 4; mt++)
#pragma unroll
      for (int nt = 0; nt < 4; nt++)
        acc[mt][nt] = __builtin_amdgcn_mfma_f32_16x16x32_bf16(a[mt], bb[nt], acc[mt][nt], 0, 0, 0);
  }
#pragma unroll
  for (int nt = 0; nt < 4; nt++) {
    int col = n0 + nt * 16 + l16;
    float bias = (col >= 256) ? g_b1[col - 256] : 0.f;
#pragma unroll
    for (int mt = 0; mt < 4; mt++) {
      int m = m0 + mt * 16 + q * 4;
#pragma unroll
      for (int r = 0; r < 4; r++)
        uv[(size_t)(m + r) * 512 + col] = acc[mt][nt][r] + bias;
    }
  }
}

// ---------------- main fused relation kernel ----------------
// block = (b, i): rows j in [0,64). 256 thr = 4 waves; wave w owns cols
// [w*64, w*64+64) as nt=2 x 32. acc = 2mt x 2nt x 16 = 64 AGPR.
// LDS: A row j at lds[j*280] (272 elems); H row j at lds[j*256], chunk
// swizzle c^(j&7), overlays A after all A reads. 35840 B -> 4 blocks/CU.

#define ASH 280                  // 560B row = 35*16B
#define LDS_SHORTS (64 * ASH)    // 17920 shorts = 35840 B

__global__ __launch_bounds__(256, 3)
void relnet_main(const short* __restrict__ xb, const short* __restrict__ Wc,
                 const short* __restrict__ W2t, const short* __restrict__ W3t,
                 const float* __restrict__ uv, const float* __restrict__ g_b2,
                 const float* __restrict__ g_b3, float* __restrict__ rel) {
  __shared__ short lds[LDS_SHORTS];

  const int tid = threadIdx.x;
  const int bi = blockIdx.x;
  const int b = bi >> 6, i = bi & 63;
  const int lane = tid & 63, wave = tid >> 6;
  const int l32 = lane & 31, half = lane >> 5;
  const int n0 = wave * 64;          // 64-col strip per wave (nt=2 x 32)
  const int rowbase = b * 64;
  const int swr = l32 & 7;           // H-row swizzle key

  f32x16 acc[2][2];
#pragma unroll
  for (int mt = 0; mt < 2; mt++)
#pragma unroll
    for (int nt = 0; nt < 2; nt++)
#pragma unroll
      for (int r = 0; r < 16; r++) acc[mt][nt][r] = 0.f;

  // ---- stage pair products (K=272): 64 rows x 34 chunks = 2176, runtime loop
  {
    const short* xi = xb + (size_t)(rowbase + i) * KX;
    for (int idx = tid; idx < 64 * 34; idx += 256) {
      int j = idx / 34, c = idx - j * 34;
      int k = c * 8;
      u32x4 aj = *(const u32x4*)(xb + (size_t)(rowbase + j) * KX + k);
      u32x4 ai = *(const u32x4*)(xi + k);
      *(frag8*)(&lds[j * ASH + k]) = pk_mul4(aj, ai);
    }
  }
  __syncthreads();

  // ---- layer 1: 17 k-steps, 1-deep B prefetch, A direct from LDS ----
  {
    const short* wc0 = Wc + (size_t)(n0 + l32) * KX + half * 8;
    const short* wc1 = Wc + (size_t)(n0 + 32 + l32) * KX + half * 8;
    frag8 b0 = *(const frag8*)(wc0);
    frag8 b1 = *(const frag8*)(wc1);
#pragma unroll
    for (int ks = 0; ks < 17; ks++) {
      frag8 bn0, bn1;
      if (ks < 16) {
        bn0 = *(const frag8*)(wc0 + (ks + 1) * 16);
        bn1 = *(const frag8*)(wc1 + (ks + 1) * 16);
      }
      frag8 a[2];
#pragma unroll
      for (int mt = 0; mt < 2; mt++)
        a[mt] = *(const frag8*)(&lds[(mt * 32 + l32) * ASH + ks * 16 + half * 8]);
#pragma unroll
      for (int mt = 0; mt < 2; mt++) {
        acc[mt][0] = __builtin_amdgcn_mfma_f32_32x32x16_bf16(a[mt], b0, acc[mt][0], 0, 0, 0);
        acc[mt][1] = __builtin_amdgcn_mfma_f32_32x32x16_bf16(a[mt], b1, acc[mt][1], 0, 0, 0);
      }
      b0 = bn0; b1 = bn1;
    }
  }
  __syncthreads();  // all A reads done before H overwrites

  // ---- layer 1 epilogue: h1 = relu(acc + u[j] + v[i] + b1) -> H (packed) ----
  {
    const float* ub = uv + (size_t)rowbase * 512;
    const float* vp = uv + (size_t)(rowbase + i) * 512 + 256;  // v(i)+b1
#pragma unroll
    for (int nt = 0; nt < 2; nt++) {
      int col = n0 + nt * 32 + l32;
      int cb = (n0 + nt * 32) >> 3;
      float vv = vp[col];
#pragma unroll
      for (int mt = 0; mt < 2; mt++) {
#pragma unroll
        for (int r = 0; r < 16; r += 2) {
          int rb0 = (r & 3) + 8 * (r >> 2) + 4 * half;
          int m0r = mt * 32 + rb0;   // = j row
          float x0 = fmaxf(acc[mt][nt][r]     + ub[(size_t)m0r * 512 + col] + vv, 0.f);
          float x1 = fmaxf(acc[mt][nt][r + 1] + ub[(size_t)(m0r + 1) * 512 + col] + vv, 0.f);
          unsigned pk = pk_bf16(x0, x1);
          int sw0 = (r & 3) + 4 * half;
          lds[m0r * 256 + (((cb + (l32 >> 3)) ^ sw0) << 3) + (l32 & 7)] = (short)(pk & 0xffffu);
          lds[(m0r + 1) * 256 + (((cb + (l32 >> 3)) ^ (sw0 + 1)) << 3) + (l32 & 7)] = (short)(pk >> 16);
        }
#pragma unroll
        for (int r = 0; r < 16; r++) acc[mt][nt][r] = 0.f;
      }
    }
  }
  __syncthreads();

  // ---- layer 2: h2 = relu(h1 @ W2 + b2), 16 k-steps ----
  {
    const short* w20 = W2t + (size_t)(n0 + l32) * 256 + half * 8;
    const short* w21 = W2t + (size_t)(n0 + 32 + l32) * 256 + half * 8;
    frag8 b0 = *(const frag8*)(w20);
    frag8 b1 = *(const frag8*)(w21);
#pragma unroll
    for (int ks = 0; ks < 16; ks++) {
      frag8 bn0, bn1;
      if (ks < 15) {
        bn0 = *(const frag8*)(w20 + (ks + 1) * 16);
        bn1 = *(const frag8*)(w21 + (ks + 1) * 16);
      }
      frag8 a[2];
#pragma unroll
      for (int mt = 0; mt < 2; mt++)
        a[mt] = *(const frag8*)(&lds[(mt * 32 + l32) * 256 + (((2 * ks + half) ^ swr) << 3)]);
#pragma unroll
      for (int mt = 0; mt < 2; mt++) {
        acc[mt][0] = __builtin_amdgcn_mfma_f32_32x32x16_bf16(a[mt], b0, acc[mt][0], 0, 0, 0);
        acc[mt][1] = __builtin_amdgcn_mfma_f32_32x32x16_bf16(a[mt], b1, acc[mt][1], 0, 0, 0);
      }
      b0 = bn0; b1 = bn1;
    }
  }
  __syncthreads();  // all reads of h1 done before h2 overwrites

  // ---- layer 2 epilogue (packed) ----
#pragma unroll
  for (int nt = 0; nt < 2; nt++) {
    int col = n0 + nt * 32 + l32;
    int cb = (n0 + nt * 32) >> 3;
    float b2 = g_b2[col];
#pragma unroll
    for (int mt = 0; mt < 2; mt++) {
#pragma unroll
      for (int r = 0; r < 16; r += 2) {
        int rb0 = (r & 3) + 8 * (r >> 2) + 4 * half;
        int m0r = mt * 32 + rb0;
        float x0 = fmaxf(acc[mt][nt][r] + b2, 0.f);
        float x1 = fmaxf(acc[mt][nt][r + 1] + b2, 0.f);
        unsigned pk = pk_bf16(x0, x1);
        int sw0 = (r & 3) + 4 * half;
        lds[m0r * 256 + (((cb + (l32 >> 3)) ^ sw0) << 3) + (l32 & 7)] = (short)(pk & 0xffffu);
        lds[(m0r + 1) * 256 + (((cb + (l32 >> 3)) ^ (sw0 + 1)) << 3) + (l32 & 7)] = (short)(pk >> 16);
      }
#pragma unroll
      for (int r = 0; r < 16; r++) acc[mt][nt][r] = 0.f;
    }
  }
  __syncthreads();

  // ---- layer 3: h3 = relu(h2 @ W3 + b3); reduce over j; atomic ----
  {
    const short* w30 = W3t + (size_t)(n0 + l32) * 256 + half * 8;
    const short* w31 = W3t + (size_t)(n0 + 32 + l32) * 256 + half * 8;
    frag8 b0 = *(const frag8*)(w30);
    frag8 b1 = *(const frag8*)(w31);
#pragma unroll
    for (int ks = 0; ks < 16; ks++) {
      frag8 bn0, bn1;
      if (ks < 15) {
        bn0 = *(const frag8*)(w30 + (ks + 1) * 16);
        bn1 = *(const frag8*)(w31 + (ks + 1) * 16);
      }
      frag8 a[2];
#pragma unroll
      for (int mt = 0; mt < 2; mt++)
        a[mt] = *(const frag8*)(&lds[(mt * 32 + l32) * 256 + (((2 * ks + half) ^ swr) << 3)]);
#pragma unroll
      for (int mt = 0; mt < 2; mt++) {
        acc[mt][0] = __builtin_amdgcn_mfma_f32_32x32x16_bf16(a[mt], b0, acc[mt][0], 0, 0, 0);
        acc[mt][1] = __builtin_amdgcn_mfma_f32_32x32x16_bf16(a[mt], b1, acc[mt][1], 0, 0, 0);
      }
      b0 = bn0; b1 = bn1;
    }
  }
#pragma unroll
  for (int nt = 0; nt < 2; nt++) {
    int col = n0 + nt * 32 + l32;
    float b3 = g_b3[col];
    float s = 0.f;
#pragma unroll
    for (int mt = 0; mt < 2; mt++)
#pragma unroll
      for (int r = 0; r < 16; r++)
        s += fmaxf(acc[mt][nt][r] + b3, 0.f);
    s += __shfl_xor(s, 32, 64);
    if (half == 0) atomicAdd(&rel[b * 256 + col], s);
  }
}

// ---------------- f-network (fp32, exact) ----------------
__global__ __launch_bounds__(256)
void fnet(const float* __restrict__ rel, const float* __restrict__ f_w1,
          const float* __restrict__ f_b1, const float* __restrict__ f_w2,
          const float* __restrict__ f_b2, const float* __restrict__ f_w3,
          const float* __restrict__ f_b3, float* __restrict__ out) {
  int b = blockIdx.x, t = threadIdx.x;
  __shared__ float y0[256], y1[256], y2[256];
  y0[t] = rel[b * 256 + t];
  __syncthreads();
  float s = f_b1[t];
#pragma unroll 8
  for (int k = 0; k < 256; k++) s += y0[k] * f_w1[k * 256 + t];
  y1[t] = fmaxf(s, 0.f);
  __syncthreads();
  s = f_b2[t];
#pragma unroll 8
  for (int k = 0; k < 256; k++) s += y1[k] * f_w2[k * 256 + t];
  y2[t] = fmaxf(s, 0.f);
  __syncthreads();
  if (t < 10) {
    float s2 = f_b3[t];
#pragma unroll 8
    for (int k = 0; k < 256; k++) s2 += y2[k] * f_w3[k * 10 + t];
    out[b * 10 + t] = s2;
  }
}

// ---------------- launch ----------------
extern "C" void kernel_launch(void* const* d_in, const int* in_sizes, int n_in,
                              void* d_out, int out_size, void* d_ws, size_t ws_size,
                              hipStream_t stream) {
  const float* sent  = (const float*)d_in[0];
  const float* coord = (const float*)d_in[1];
  const float* g_w1  = (const float*)d_in[2];
  const float* g_b1  = (const float*)d_in[3];
  const float* g_w2  = (const float*)d_in[4];
  const float* g_b2  = (const float*)d_in[5];
  const float* g_w3  = (const float*)d_in[6];
  const float* g_b3  = (const float*)d_in[7];
  const float* f_w1  = (const float*)d_in[8];
  const float* f_b1  = (const float*)d_in[9];
  const float* f_w2  = (const float*)d_in[10];
  const float* f_b2  = (const float*)d_in[11];
  const float* f_w3  = (const float*)d_in[12];
  const float* f_b3  = (const float*)d_in[13];
  float* out = (float*)d_out;

  char* ws = (char*)d_ws;
  size_t off = 0;
  auto alloc = [&](size_t bytes) {
    char* p = ws + off;
    off += (bytes + 255) & ~(size_t)255;
    return p;
  };
  short* xb  = (short*)alloc((size_t)2048 * KX * 2);
  short* Wab = (short*)alloc((size_t)512 * KX * 2);
  short* Wc  = (short*)alloc((size_t)256 * KX * 2);
  short* W2t = (short*)alloc((size_t)256 * 256 * 2);
  short* W3t = (short*)alloc((size_t)256 * 256 * 2);
  float* uv  = (float*)alloc((size_t)2048 * 512 * 4);
  float* rel = (float*)alloc((size_t)32 * 256 * 4);

  prep<<<388, 256, 0, stream>>>(sent, coord, g_w1, g_w2, g_w3, xb, Wab, Wc, W2t, W3t, rel);
  uv_gemm<<<dim3(32, 8), 64, 0, stream>>>(xb, Wab, g_b1, uv);
  relnet_main<<<2048, 256, 0, stream>>>(xb, Wc, W2t, W3t, uv, g_b2, g_b3, rel);
  fnet<<<32, 256, 0, stream>>>(rel, f_w1, f_b1, f_w2, f_b2, f_w3, f_b3, out);
}

// Round 11
// 182.792 us; speedup vs baseline: 1.2594x; 1.2594x over previous
//
#include <hip/hip_runtime.h>
#include <hip/hip_bf16.h>

// RelationsNetwork on MI355X.
// Decomposition: h1 = relu(u[j] + v[i] + (x_i*x_j)@W_c + b1), u=x@W_a, v=x@W_b
// where g_w1 = [W_a; W_b; W_c] (rows 0:258, 258:516, 516:774).
// Round-11 = r8 (best, 73.2us) + B-stall fixes only. Geometry is LOCKED:
// N=256 un-splittable (layer2's K = all 256 h1 cols), M=128/4-wave/acc-128
// is the proven optimum (r9 8-wave spilled at 128-reg cap; r10 M=64 regressed).
//  (a) 2-deep B prefetch (bq[3] rotation): load-use distance ~110 -> ~220cyc
//      >= L2 latency; +8 VGPR (116->~124, total 252 <= 256 cap, no spill)
//  (b) initial B loads of each layer hoisted above the preceding barrier
//      (LDS-independent; overlap barrier drain)
//  (c) ASH 152->156: A-read bank pattern 14*l32%32 = 2-way only (was 4-way);
//      LDS 79872B x 2 blocks = 159744 <= 163840.
// Block=(b,i-pair), M=128, 32x32x16 MFMA, acc 128 AGPR, (256,2).
// LDS: A1 128x156 @0, A2 @19968, H 128x256 swizzled @0 (after all A reads).

typedef __attribute__((ext_vector_type(4))) float f32x4;
typedef __attribute__((ext_vector_type(16))) float f32x16;
typedef __attribute__((ext_vector_type(8))) short frag8;   // 8 bf16 = 4 VGPR
typedef __attribute__((ext_vector_type(4))) unsigned u32x4;

__device__ __forceinline__ float bf2f(short s) {
  return __uint_as_float(((unsigned)(unsigned short)s) << 16);
}
__device__ __forceinline__ short f2bf(float f) {
  unsigned u = __float_as_uint(f);
  return (short)((u + 0x7fffu + ((u >> 16) & 1u)) >> 16);
}

// pack two f32 -> one dword of two bf16 (lo, hi), RNE
__device__ __forceinline__ unsigned pk_bf16(float lo, float hi) {
#if __has_builtin(__builtin_amdgcn_cvt_pk_bf16_f32)
  return __builtin_bit_cast(unsigned, __builtin_amdgcn_cvt_pk_bf16_f32(lo, hi));
#else
  unsigned ul = __float_as_uint(lo), uh = __float_as_uint(hi);
  ul = (ul + 0x7fffu + ((ul >> 16) & 1u)) >> 16;
  uh = (uh + 0x7fffu + ((uh >> 16) & 1u)) & 0xffff0000u;
  return ul | uh;
#endif
}

// elementwise bf16 product of two bf16x2 dwords
__device__ __forceinline__ unsigned pk_mul_bf16(unsigned a, unsigned b) {
  float al = __uint_as_float(a << 16);
  float ah = __uint_as_float(a & 0xffff0000u);
  float bl = __uint_as_float(b << 16);
  float bh = __uint_as_float(b & 0xffff0000u);
  return pk_bf16(al * bl, ah * bh);
}

__device__ __forceinline__ frag8 pk_mul4(u32x4 a, u32x4 b) {
  u32x4 r;
#pragma unroll
  for (int t = 0; t < 4; t++) r[t] = pk_mul_bf16(a[t], b[t]);
  return __builtin_bit_cast(frag8, r);
}

#define KX 288   // xb row stride (padded); K iterated = 272 (144 + 128)

// ---------------- merged prep kernel ----------------
// regions by blockIdx.x:
//   [0,288)    build_x:  xb[(b*64+s)*288+k] = bf16(x[b,s,k])
//   [288,328)  Wab:  [n][k] n<256 -> W_a col n ; n>=256 -> W_b col n-256
//   [328,348)  Wc:   [n][k] = g_w1[516+k][n]
//   [348,364)  W2t:  [n][k] = g_w2[k][n]
//   [364,380)  W3t:  [n][k] = g_w3[k][n]
//   [380,388)  zero rel
__global__ __launch_bounds__(256)
void prep(const float* __restrict__ sent, const float* __restrict__ coord,
          const float* __restrict__ g_w1, const float* __restrict__ g_w2,
          const float* __restrict__ g_w3,
          short* __restrict__ xb, short* __restrict__ Wab, short* __restrict__ Wc,
          short* __restrict__ W2t, short* __restrict__ W3t, float* __restrict__ rel) {
  __shared__ short tile[64 * 66];  // odd-dword stride: conflict-free transpose
  const int blk = blockIdx.x, t = threadIdx.x;

  if (blk < 288) {
    long idx0 = ((long)blk * 256 + t) * 8;
#pragma unroll
    for (int e = 0; e < 8; e++) {
      long idx = idx0 + e;
      int row = (int)(idx / KX), k = (int)(idx - (long)row * KX);
      float v = 0.f;
      if (k < 256)      v = sent[(size_t)row * 256 + k];
      else if (k < 258) v = coord[row * 2 + (k - 256)];
      xb[idx] = f2bf(v);
    }
    return;
  }

  const int nc = t & 63, r4 = t >> 6;  // read: 4 rows x 64 cols per pass
  if (blk < 328) {  // Wab
    int tt = blk - 288, kt = tt >> 3, nt = tt & 7;
    int k0 = kt * 64, n0 = nt * 64;
    for (int p = 0; p < 16; p++) {
      int kl = p * 4 + r4, k = k0 + kl, n = n0 + nc;
      float v = 0.f;
      if (k < 258) {
        int row = (n < 256) ? k : 258 + k;
        int col = (n < 256) ? n : n - 256;
        v = g_w1[(size_t)row * 256 + col];
      }
      tile[kl * 66 + nc] = f2bf(v);
    }
    __syncthreads();
    for (int p = 0; p < 16; p++) {
      int nl = p * 4 + r4;
      if (k0 + nc < KX) Wab[(size_t)(n0 + nl) * KX + k0 + nc] = tile[nc * 66 + nl];
    }
    return;
  }
  if (blk < 348) {  // Wc
    int tt = blk - 328, kt = tt >> 2, nt = tt & 3;
    int k0 = kt * 64, n0 = nt * 64;
    for (int p = 0; p < 16; p++) {
      int kl = p * 4 + r4, k = k0 + kl;
      float v = (k < 258) ? g_w1[(size_t)(516 + k) * 256 + n0 + nc] : 0.f;
      tile[kl * 66 + nc] = f2bf(v);
    }
    __syncthreads();
    for (int p = 0; p < 16; p++) {
      int nl = p * 4 + r4;
      if (k0 + nc < KX) Wc[(size_t)(n0 + nl) * KX + k0 + nc] = tile[nc * 66 + nl];
    }
    return;
  }
  if (blk < 380) {  // W2t / W3t
    int tt = blk - 348;
    const float* W = (tt < 16) ? g_w2 : g_w3;
    short* Wt = (tt < 16) ? W2t : W3t;
    tt &= 15;
    int k0 = (tt >> 2) * 64, n0 = (tt & 3) * 64;
    for (int p = 0; p < 16; p++) {
      int kl = p * 4 + r4;
      tile[kl * 66 + nc] = f2bf(W[(size_t)(k0 + kl) * 256 + n0 + nc]);
    }
    __syncthreads();
    for (int p = 0; p < 16; p++) {
      int nl = p * 4 + r4;
      Wt[(size_t)(n0 + nl) * 256 + k0 + nc] = tile[nc * 66 + nl];
    }
    return;
  }
  // zero rel: 8 blocks x 256 threads x 1 float4
  {
    int bb = blk - 380;
    ((f32x4*)rel)[bb * 256 + t] = (f32x4){0.f, 0.f, 0.f, 0.f};
  }
}

// ---------------- u/v GEMM: uv[m][0:256]=x@W_a, uv[m][256:512]=x@W_b + b1 ----------------
// one wave per block, 256 blocks (32 m-tiles x 8 n-tiles); 16x16x32 (known-good)

__global__ __launch_bounds__(64)
void uv_gemm(const short* __restrict__ xb, const short* __restrict__ Wab,
             const float* __restrict__ g_b1, float* __restrict__ uv) {
  const int m0 = blockIdx.x * 64;
  const int n0 = blockIdx.y * 64;
  const int lane = threadIdx.x;
  const int q = lane >> 4, l16 = lane & 15;

  f32x4 acc[4][4];
#pragma unroll
  for (int mt = 0; mt < 4; mt++)
#pragma unroll
    for (int nt = 0; nt < 4; nt++) acc[mt][nt] = (f32x4){0.f, 0.f, 0.f, 0.f};

  for (int k0 = 0; k0 < KX; k0 += 32) {
    frag8 a[4], bb[4];
#pragma unroll
    for (int mt = 0; mt < 4; mt++)
      a[mt] = *(const frag8*)(xb + (size_t)(m0 + mt * 16 + l16) * KX + k0 + q * 8);
#pragma unroll
    for (int nt = 0; nt < 4; nt++)
      bb[nt] = *(const frag8*)(Wab + (size_t)(n0 + nt * 16 + l16) * KX + k0 + q * 8);
#pragma unroll
    for (int mt = 0; mt < 4; mt++)
#pragma unroll
      for (int nt = 0; nt < 4; nt++)
        acc[mt][nt] = __builtin_amdgcn_mfma_f32_16x16x32_bf16(a[mt], bb[nt], acc[mt][nt], 0, 0, 0);
  }
#pragma unroll
  for (int nt = 0; nt < 4; nt++) {
    int col = n0 + nt * 16 + l16;
    float bias = (col >= 256) ? g_b1[col - 256] : 0.f;
#pragma unroll
    for (int mt = 0; mt < 4; mt++) {
      int m = m0 + mt * 16 + q * 4;
#pragma unroll
      for (int r = 0; r < 4; r++)
        uv[(size_t)(m + r) * 512 + col] = acc[mt][nt][r] + bias;
    }
  }
}

// ---------------- main fused relation kernel ----------------
// block = (b, ipair): rows m in [0,128): j = m&63, i = i0 + (m>>6).
// LDS: A1 half (K 0..144) rows at lds[m*156]; A2 half (K 144..272) at
// lds[A2OFF + m*156]; H view row m at lds[m*256], chunk swizzle c^(m&7).

#define ASH 156                     // 312B row; bank step 14*l32%32 -> 2-way only
#define A2OFF (128 * ASH)           // 19968 shorts
#define LDS_SHORTS (2 * 128 * ASH)  // 39936 shorts = 79872 B; 2 blk = 159744 <= 163840

__global__ __launch_bounds__(256, 2)
void relnet_main(const short* __restrict__ xb, const short* __restrict__ Wc,
                 const short* __restrict__ W2t, const short* __restrict__ W3t,
                 const float* __restrict__ uv, const float* __restrict__ g_b2,
                 const float* __restrict__ g_b3, float* __restrict__ rel) {
  __shared__ short lds[LDS_SHORTS];

  const int tid = threadIdx.x;
  const int bi = blockIdx.x;
  const int b = bi >> 5, ip = bi & 31;
  const int i0 = ip * 2;
  const int lane = tid & 63, wave = tid >> 6;
  const int l32 = lane & 31, half = lane >> 5;
  const int n0 = wave * 64;
  const int rowbase = b * 64;
  const int swr = l32 & 7;  // H-row swizzle key

  f32x16 acc[4][2];
#pragma unroll
  for (int mt = 0; mt < 4; mt++)
#pragma unroll
    for (int nt = 0; nt < 2; nt++)
#pragma unroll
      for (int r = 0; r < 16; r++) acc[mt][nt][r] = 0.f;

  // ---- stage half1 (K 0..144): 128 rows x 18 chunks / 256 thr = 9 each ----
#pragma unroll
  for (int it = 0; it < 9; it++) {
    int idx = tid + it * 256;
    int j = idx / 18, c = idx - j * 18;
    int k = c * 8;
    u32x4 aj = *(const u32x4*)(xb + (size_t)(rowbase + (j & 63)) * KX + k);
    u32x4 ai = *(const u32x4*)(xb + (size_t)(rowbase + i0 + (j >> 6)) * KX + k);
    *(frag8*)(&lds[j * ASH + k]) = pk_mul4(aj, ai);
  }

  // ---- layer 1 B pipeline: 2-deep, initial loads hoisted above barrier ----
  const short* wc0 = Wc + (size_t)(n0 + l32) * KX + half * 8;
  const short* wc1 = Wc + (size_t)(n0 + 32 + l32) * KX + half * 8;
  frag8 bq0[3], bq1[3];
  bq0[0] = *(const frag8*)(wc0);
  bq1[0] = *(const frag8*)(wc1);
  bq0[1] = *(const frag8*)(wc0 + 16);
  bq1[1] = *(const frag8*)(wc1 + 16);
  __syncthreads();

  // ---- layer 1 half1: ks 0..8 (A1) ----
#pragma unroll
  for (int ks = 0; ks < 9; ks++) {
    if (ks + 2 < 17) {
      bq0[(ks + 2) % 3] = *(const frag8*)(wc0 + (ks + 2) * 16);
      bq1[(ks + 2) % 3] = *(const frag8*)(wc1 + (ks + 2) * 16);
    }
    frag8 a[4];
#pragma unroll
    for (int mt = 0; mt < 4; mt++)
      a[mt] = *(const frag8*)(&lds[(mt * 32 + l32) * ASH + ks * 16 + half * 8]);
#pragma unroll
    for (int mt = 0; mt < 4; mt++) {
      acc[mt][0] = __builtin_amdgcn_mfma_f32_32x32x16_bf16(a[mt], bq0[ks % 3], acc[mt][0], 0, 0, 0);
      acc[mt][1] = __builtin_amdgcn_mfma_f32_32x32x16_bf16(a[mt], bq1[ks % 3], acc[mt][1], 0, 0, 0);
    }
  }

  // ---- stage half2 (K 144..272) into DISJOINT region A2 (no barrier needed
  //      before these writes; overlaps other waves' half1 MFMAs) ----
#pragma unroll
  for (int it = 0; it < 8; it++) {
    int idx = tid + it * 256;
    int j = idx >> 4, c = idx & 15;
    int k = 144 + c * 8;
    u32x4 aj = *(const u32x4*)(xb + (size_t)(rowbase + (j & 63)) * KX + k);
    u32x4 ai = *(const u32x4*)(xb + (size_t)(rowbase + i0 + (j >> 6)) * KX + k);
    *(frag8*)(&lds[A2OFF + j * ASH + c * 8]) = pk_mul4(aj, ai);
  }
  __syncthreads();

  // ---- layer 1 half2: ks 9..16 (A2); B pipeline continues seamlessly ----
#pragma unroll
  for (int ks = 9; ks < 17; ks++) {
    if (ks + 2 < 17) {
      bq0[(ks + 2) % 3] = *(const frag8*)(wc0 + (ks + 2) * 16);
      bq1[(ks + 2) % 3] = *(const frag8*)(wc1 + (ks + 2) * 16);
    }
    frag8 a[4];
#pragma unroll
    for (int mt = 0; mt < 4; mt++)
      a[mt] = *(const frag8*)(&lds[A2OFF + (mt * 32 + l32) * ASH + (ks - 9) * 16 + half * 8]);
#pragma unroll
    for (int mt = 0; mt < 4; mt++) {
      acc[mt][0] = __builtin_amdgcn_mfma_f32_32x32x16_bf16(a[mt], bq0[ks % 3], acc[mt][0], 0, 0, 0);
      acc[mt][1] = __builtin_amdgcn_mfma_f32_32x32x16_bf16(a[mt], bq1[ks % 3], acc[mt][1], 0, 0, 0);
    }
  }
  __syncthreads();  // all A reads (both halves) done before H overwrites

  // ---- layer 1 epilogue: h1 = relu(acc + u[j] + v[i] + b1) -> H (packed) ----
  {
    const float* ub = uv + (size_t)rowbase * 512;
    const float* v0p = uv + (size_t)(rowbase + i0) * 512 + 256;      // v(i0) + b1
    const float* v1p = uv + (size_t)(rowbase + i0 + 1) * 512 + 256;  // v(i1) + b1
#pragma unroll
    for (int nt = 0; nt < 2; nt++) {
      int col = n0 + nt * 32 + l32;
      int cb = (n0 + nt * 32) >> 3;
      float vv0 = v0p[col], vv1 = v1p[col];
#pragma unroll
      for (int mt = 0; mt < 4; mt++) {
        float vv = (mt < 2) ? vv0 : vv1;
#pragma unroll
        for (int r = 0; r < 16; r += 2) {
          int rb0 = (r & 3) + 8 * (r >> 2) + 4 * half;
          int jm0 = (mt & 1) * 32 + rb0;
          float x0 = fmaxf(acc[mt][nt][r]     + ub[(size_t)jm0 * 512 + col] + vv, 0.f);
          float x1 = fmaxf(acc[mt][nt][r + 1] + ub[(size_t)(jm0 + 1) * 512 + col] + vv, 0.f);
          unsigned pk = pk_bf16(x0, x1);
          int m0r = mt * 32 + rb0;
          int sw0 = (r & 3) + 4 * half;
          lds[m0r * 256 + (((cb + (l32 >> 3)) ^ sw0) << 3) + (l32 & 7)] = (short)(pk & 0xffffu);
          lds[(m0r + 1) * 256 + (((cb + (l32 >> 3)) ^ (sw0 + 1)) << 3) + (l32 & 7)] = (short)(pk >> 16);
        }
#pragma unroll
        for (int r = 0; r < 16; r++) acc[mt][nt][r] = 0.f;
      }
    }
  }
  // ---- layer 2 initial B loads (LDS-independent) above the barrier ----
  const short* w20 = W2t + (size_t)(n0 + l32) * 256 + half * 8;
  const short* w21 = W2t + (size_t)(n0 + 32 + l32) * 256 + half * 8;
  bq0[0] = *(const frag8*)(w20);
  bq1[0] = *(const frag8*)(w21);
  bq0[1] = *(const frag8*)(w20 + 16);
  bq1[1] = *(const frag8*)(w21 + 16);
  __syncthreads();

  // ---- layer 2: h2 = relu(h1 @ W2 + b2), 16 k-steps, 2-deep B ----
#pragma unroll
  for (int ks = 0; ks < 16; ks++) {
    if (ks + 2 < 16) {
      bq0[(ks + 2) % 3] = *(const frag8*)(w20 + (ks + 2) * 16);
      bq1[(ks + 2) % 3] = *(const frag8*)(w21 + (ks + 2) * 16);
    }
    frag8 a[4];
#pragma unroll
    for (int mt = 0; mt < 4; mt++)
      a[mt] = *(const frag8*)(&lds[(mt * 32 + l32) * 256 + (((2 * ks + half) ^ swr) << 3)]);
#pragma unroll
    for (int mt = 0; mt < 4; mt++) {
      acc[mt][0] = __builtin_amdgcn_mfma_f32_32x32x16_bf16(a[mt], bq0[ks % 3], acc[mt][0], 0, 0, 0);
      acc[mt][1] = __builtin_amdgcn_mfma_f32_32x32x16_bf16(a[mt], bq1[ks % 3], acc[mt][1], 0, 0, 0);
    }
  }
  __syncthreads();  // all reads of h1 done before h2 overwrites

  // ---- layer 2 epilogue (packed) ----
#pragma unroll
  for (int nt = 0; nt < 2; nt++) {
    int col = n0 + nt * 32 + l32;
    int cb = (n0 + nt * 32) >> 3;
    float b2 = g_b2[col];
#pragma unroll
    for (int mt = 0; mt < 4; mt++) {
#pragma unroll
      for (int r = 0; r < 16; r += 2) {
        int rb0 = (r & 3) + 8 * (r >> 2) + 4 * half;
        float x0 = fmaxf(acc[mt][nt][r] + b2, 0.f);
        float x1 = fmaxf(acc[mt][nt][r + 1] + b2, 0.f);
        unsigned pk = pk_bf16(x0, x1);
        int m0r = mt * 32 + rb0;
        int sw0 = (r & 3) + 4 * half;
        lds[m0r * 256 + (((cb + (l32 >> 3)) ^ sw0) << 3) + (l32 & 7)] = (short)(pk & 0xffffu);
        lds[(m0r + 1) * 256 + (((cb + (l32 >> 3)) ^ (sw0 + 1)) << 3) + (l32 & 7)] = (short)(pk >> 16);
      }
#pragma unroll
      for (int r = 0; r < 16; r++) acc[mt][nt][r] = 0.f;
    }
  }
  // ---- layer 3 initial B loads above the barrier ----
  const short* w30 = W3t + (size_t)(n0 + l32) * 256 + half * 8;
  const short* w31 = W3t + (size_t)(n0 + 32 + l32) * 256 + half * 8;
  bq0[0] = *(const frag8*)(w30);
  bq1[0] = *(const frag8*)(w31);
  bq0[1] = *(const frag8*)(w30 + 16);
  bq1[1] = *(const frag8*)(w31 + 16);
  __syncthreads();

  // ---- layer 3: h3 = relu(h2 @ W3 + b3); reduce over (i,j); atomic ----
#pragma unroll
  for (int ks = 0; ks < 16; ks++) {
    if (ks + 2 < 16) {
      bq0[(ks + 2) % 3] = *(const frag8*)(w30 + (ks + 2) * 16);
      bq1[(ks + 2) % 3] = *(const frag8*)(w31 + (ks + 2) * 16);
    }
    frag8 a[4];
#pragma unroll
    for (int mt = 0; mt < 4; mt++)
      a[mt] = *(const frag8*)(&lds[(mt * 32 + l32) * 256 + (((2 * ks + half) ^ swr) << 3)]);
#pragma unroll
    for (int mt = 0; mt < 4; mt++) {
      acc[mt][0] = __builtin_amdgcn_mfma_f32_32x32x16_bf16(a[mt], bq0[ks % 3], acc[mt][0], 0, 0, 0);
      acc[mt][1] = __builtin_amdgcn_mfma_f32_32x32x16_bf16(a[mt], bq1[ks % 3], acc[mt][1], 0, 0, 0);
    }
  }
#pragma unroll
  for (int nt = 0; nt < 2; nt++) {
    int col = n0 + nt * 32 + l32;
    float b3 = g_b3[col];
    float s = 0.f;
#pragma unroll
    for (int mt = 0; mt < 4; mt++)
#pragma unroll
      for (int r = 0; r < 16; r++)
        s += fmaxf(acc[mt][nt][r] + b3, 0.f);
    s += __shfl_xor(s, 32, 64);
    if (half == 0) atomicAdd(&rel[b * 256 + col], s);
  }
}

// ---------------- f-network (fp32, exact) ----------------
__global__ __launch_bounds__(256)
void fnet(const float* __restrict__ rel, const float* __restrict__ f_w1,
          const float* __restrict__ f_b1, const float* __restrict__ f_w2,
          const float* __restrict__ f_b2, const float* __restrict__ f_w3,
          const float* __restrict__ f_b3, float* __restrict__ out) {
  int b = blockIdx.x, t = threadIdx.x;
  __shared__ float y0[256], y1[256], y2[256];
  y0[t] = rel[b * 256 + t];
  __syncthreads();
  float s = f_b1[t];
#pragma unroll 8
  for (int k = 0; k < 256; k++) s += y0[k] * f_w1[k * 256 + t];
  y1[t] = fmaxf(s, 0.f);
  __syncthreads();
  s = f_b2[t];
#pragma unroll 8
  for (int k = 0; k < 256; k++) s += y1[k] * f_w2[k * 256 + t];
  y2[t] = fmaxf(s, 0.f);
  __syncthreads();
  if (t < 10) {
    float s2 = f_b3[t];
#pragma unroll 8
    for (int k = 0; k < 256; k++) s2 += y2[k] * f_w3[k * 10 + t];
    out[b * 10 + t] = s2;
  }
}

// ---------------- launch ----------------
extern "C" void kernel_launch(void* const* d_in, const int* in_sizes, int n_in,
                              void* d_out, int out_size, void* d_ws, size_t ws_size,
                              hipStream_t stream) {
  const float* sent  = (const float*)d_in[0];
  const float* coord = (const float*)d_in[1];
  const float* g_w1  = (const float*)d_in[2];
  const float* g_b1  = (const float*)d_in[3];
  const float* g_w2  = (const float*)d_in[4];
  const float* g_b2  = (const float*)d_in[5];
  const float* g_w3  = (const float*)d_in[6];
  const float* g_b3  = (const float*)d_in[7];
  const float* f_w1  = (const float*)d_in[8];
  const float* f_b1  = (const float*)d_in[9];
  const float* f_w2  = (const float*)d_in[10];
  const float* f_b2  = (const float*)d_in[11];
  const float* f_w3  = (const float*)d_in[12];
  const float* f_b3  = (const float*)d_in[13];
  float* out = (float*)d_out;

  char* ws = (char*)d_ws;
  size_t off = 0;
  auto alloc = [&](size_t bytes) {
    char* p = ws + off;
    off += (bytes + 255) & ~(size_t)255;
    return p;
  };
  short* xb  = (short*)alloc((size_t)2048 * KX * 2);
  short* Wab = (short*)alloc((size_t)512 * KX * 2);
  short* Wc  = (short*)alloc((size_t)256 * KX * 2);
  short* W2t = (short*)alloc((size_t)256 * 256 * 2);
  short* W3t = (short*)alloc((size_t)256 * 256 * 2);
  float* uv  = (float*)alloc((size_t)2048 * 512 * 4);
  float* rel = (float*)alloc((size_t)32 * 256 * 4);

  prep<<<388, 256, 0, stream>>>(sent, coord, g_w1, g_w2, g_w3, xb, Wab, Wc, W2t, W3t, rel);
  uv_gemm<<<dim3(32, 8), 64, 0, stream>>>(xb, Wab, g_b1, uv);
  relnet_main<<<1024, 256, 0, stream>>>(xb, Wc, W2t, W3t, uv, g_b2, g_b3, rel);
  fnet<<<32, 256, 0, stream>>>(rel, f_w1, f_b1, f_w2, f_b2, f_w3, f_b3, out);
}